// Round 5
// baseline (239.602 us; speedup 1.0000x reference)
//
#include <hip/hip_runtime.h>
#include <math.h>

// NoisyTopkRouter, all-f32.
// x[ntok,384] @ {w_route,w_noise}[8,384]^T -> 16 logits/token,
// noisy = logit + noise*softplus(noise_logit), top-2 of 8, sparse softmax.
// Output: [ntok*8 probs f32 | ntok*2 indices-as-f32].
//
// R11: R10's 110.9us was a SPILL catastrophe, not a refutation of
// L1-weights: launch_bounds(256,8) capped VGPR at 32 (!) -> acc+xa+xb
// went to scratch -> WRITE_SIZE 64MB (out is 2.6MB), FETCH +30MB.
// Occupancy DID reach 80%, confirming LDS was the old cap. This round:
// same no-LDS structure at sane registers. (256,4) cap 128 (R9 allocated
// 64 naturally -> 8 waves/EU regardless); drop the explicit double-buffer
// (R6: ILP null, TLP is what pays) -> simple per-chunk loop, ~55 VGPR.
// Weights straight from global: 24KB fits L1; each wave weight-load spans
// one 128B line (8-way group redundancy collapses in the coalescer) ->
// ~4cyc/instr x 192 instr/8tok ~= 10us/CU vs R9's 31us LDS b128 floor.
// nt loads on x so the 100MB stream doesn't evict weights from L1.
// Prediction: VGPR ~56-64, WRITE 64MB->2.6MB, FETCH ~50-55MB, Occ >=70,
// kernel 110.9 -> 35-45us, dur ~145-155.

constexpr int D = 384;

typedef float vfloat4 __attribute__((ext_vector_type(4)));

__device__ __forceinline__ float4 ntload4(const float* p) {
    vfloat4 v = __builtin_nontemporal_load((const vfloat4*)p);
    return make_float4(v.x, v.y, v.z, v.w);
}

__device__ __forceinline__ float dpp_xor1(float v) {   // lane ^ 1, quad_perm [1,0,3,2]
    return __int_as_float(__builtin_amdgcn_update_dpp(
        0, __float_as_int(v), 0xB1, 0xF, 0xF, true));
}
__device__ __forceinline__ float dpp_xor2(float v) {   // lane ^ 2, quad_perm [2,3,0,1]
    return __int_as_float(__builtin_amdgcn_update_dpp(
        0, __float_as_int(v), 0x4E, 0xF, 0xF, true));
}
__device__ __forceinline__ float swz_xor4(float v) {   // ds_swizzle BitMode xor 4
    return __int_as_float(__builtin_amdgcn_ds_swizzle(__float_as_int(v), 0x101F));
}

__global__ __launch_bounds__(256, 4) void noisy_topk_router_f32(
    const float* __restrict__ x,        // [ntok,384]
    const float* __restrict__ noise,    // [ntok,8]
    const float* __restrict__ w_route,  // [8,384]
    const float* __restrict__ b_route,  // [8]
    const float* __restrict__ w_noise,  // [8,384]
    const float* __restrict__ b_noise,  // [8]
    float* __restrict__ out,            // [ntok*8 | ntok*2]
    int ntok)
{
    const int tid  = threadIdx.x;
    const int wave = tid >> 6;
    const int lane = tid & 63;
    const int tg   = lane >> 3;       // token-group 0..7 (8 lanes each)
    const int c    = lane & 7;        // d-slice 0..7
    // group handles 1 token; wave covers 8; block covers 32
    const int token = blockIdx.x * 32 + wave * 8 + tg;

    float acc[16];
#pragma unroll
    for (int e = 0; e < 16; ++e) acc[e] = 0.f;

    // chunk q (0..11): lane c covers d = q*32 + c*4 .. +4
    const float* xr  = x + (size_t)token * D + c * 4;
    const float* wre = w_route + c * 4;   // L1-resident (24KB total weights)
    const float* wno = w_noise + c * 4;

#pragma unroll
    for (int q = 0; q < 12; ++q) {
        float4 xv = ntload4(xr + q * 32);
#pragma unroll
        for (int e = 0; e < 8; ++e) {
            float4 wv = *(const float4*)(wre + e * D + q * 32);
            acc[e] += xv.x * wv.x + xv.y * wv.y + xv.z * wv.z + xv.w * wv.w;
        }
#pragma unroll
        for (int e = 0; e < 8; ++e) {
            float4 wv = *(const float4*)(wno + e * D + q * 32);
            acc[8 + e] += xv.x * wv.x + xv.y * wv.y + xv.z * wv.z + xv.w * wv.w;
        }
    }

    // full butterfly reduction over the 8 d-slices:
    // xor1 (DPP) + xor2 (DPP) + xor4 (ds_swizzle); afterwards every lane
    // of the group holds the complete 384-sum for its token.
#pragma unroll
    for (int e = 0; e < 16; ++e) acc[e] += dpp_xor1(acc[e]);
#pragma unroll
    for (int e = 0; e < 16; ++e) acc[e] += dpp_xor2(acc[e]);
#pragma unroll
    for (int e = 0; e < 16; ++e) acc[e] += swz_xor4(acc[e]);

    if (c == 0) {
        float4 n0 = *(const float4*)(noise + (size_t)token * 8);
        float4 n1 = *(const float4*)(noise + (size_t)token * 8 + 4);
        float nz[8] = {n0.x, n0.y, n0.z, n0.w, n1.x, n1.y, n1.z, n1.w};

        float4 br0 = *(const float4*)(b_route);
        float4 br1 = *(const float4*)(b_route + 4);
        float4 bn0 = *(const float4*)(b_noise);
        float4 bn1 = *(const float4*)(b_noise + 4);
        float brr[8] = {br0.x, br0.y, br0.z, br0.w, br1.x, br1.y, br1.z, br1.w};
        float bnn[8] = {bn0.x, bn0.y, bn0.z, bn0.w, bn1.x, bn1.y, bn1.z, bn1.w};

        float noisy[8];
#pragma unroll
        for (int e = 0; e < 8; ++e) {
            float lg = acc[e] + brr[e];
            float nl = acc[8 + e] + bnn[e];
            // stable softplus: max(z,0) + log1p(exp(-|z|))
            float sp = fmaxf(nl, 0.f) + log1pf(expf(-fabsf(nl)));
            noisy[e] = lg + nz[e] * sp;
        }

        // top-2, jax.lax.top_k tie-break: earliest index wins ties
        float v0 = noisy[0]; int i0 = 0;
#pragma unroll
        for (int e = 1; e < 8; ++e)
            if (noisy[e] > v0) { v0 = noisy[e]; i0 = e; }
        float v1 = -INFINITY; int i1 = 0;
#pragma unroll
        for (int e = 0; e < 8; ++e)
            if (e != i0 && noisy[e] > v1) { v1 = noisy[e]; i1 = e; }

        // 2-way softmax (other experts exactly 0)
        float ex  = expf(v1 - v0);       // v1 <= v0
        float inv = 1.f / (1.f + ex);
        float p0  = inv;
        float p1  = ex * inv;

        float pr[8];
#pragma unroll
        for (int e = 0; e < 8; ++e)
            pr[e] = (e == i0) ? p0 : ((e == i1) ? p1 : 0.f);

        float* orow = out + (size_t)token * 8;
        *(float4*)(orow)     = make_float4(pr[0], pr[1], pr[2], pr[3]);
        *(float4*)(orow + 4) = make_float4(pr[4], pr[5], pr[6], pr[7]);

        *(float2*)(out + (size_t)ntok * 8 + (size_t)token * 2) =
            make_float2((float)i0, (float)i1);
    }
}

extern "C" void kernel_launch(void* const* d_in, const int* in_sizes, int n_in,
                              void* d_out, int out_size, void* d_ws, size_t ws_size,
                              hipStream_t stream) {
    const float* x       = (const float*)d_in[0];
    const float* noise   = (const float*)d_in[1];
    const float* w_route = (const float*)d_in[2];
    const float* b_route = (const float*)d_in[3];
    const float* w_noise = (const float*)d_in[4];
    const float* b_noise = (const float*)d_in[5];
    float* out = (float*)d_out;

    const int ntok   = in_sizes[0] / D;   // 65536
    const int blocks = ntok / 32;         // 32 tokens per 256-thread block

    hipLaunchKernelGGL(noisy_topk_router_f32, dim3(blocks), dim3(256), 0, stream,
                       x, noise, w_route, b_route, w_noise, b_noise, out, ntok);
}

// Round 6
// 173.391 us; speedup vs baseline: 1.3819x; 1.3819x over previous
//
#include <hip/hip_runtime.h>
#include <math.h>

// NoisyTopkRouter, all-f32.
// x[ntok,384] @ {w_route,w_noise}[8,384]^T -> 16 logits/token,
// noisy = logit + noise*softplus(noise_logit), top-2 of 8, sparse softmax.
// Output: [ntok*8 probs f32 | ntok*2 indices-as-f32].
//
// R12: R11 refuted global/L1 weights (122us, 2x worse than LDS) -> back to
// R9's measured-best structure (58.6us). NEW signal: VALUBusy*dur ~= 25us
// across ALL variants (R8 19, R9 27, R10 29, R11 28) -- a real ~25us VALU
// workload, 4-5x the ideal FMA count. The inner dot compiles to scalar
// mul/add or at best 1 fmac per element; gfx950 has v_pk_fma_f32 (VOP3P,
// 2 f32 FMA per issue) which hipcc never auto-forms. This round, ONE
// variable: inner dot via inline-asm v_pk_fma_f32 with float2 accumulators
// (384 pk_fma/wave vs 768-1536 scalar issues). Everything else identical
// to R9. LDS model (192 ds_read_b128 x 12cyc x 32 waves/CU ~= 31us/CU) is
// the co-limiter and becomes the floor.
// Prediction: VGPR 64->~80, VALU-time 27->~12us, kernel 58.6->40-47us,
// dur ~150-158. If confirmed LDS-bound after, R13 = T=2 pairing (LDS/2).

constexpr int D = 384;

typedef float v2f __attribute__((ext_vector_type(2)));

__device__ __forceinline__ void pk_fma(v2f& a, v2f b, v2f c) {
    // a = b * c + a  (2x f32 per issue, VOP3P)
    asm("v_pk_fma_f32 %0, %1, %2, %0" : "+v"(a) : "v"(b), "v"(c));
}

__device__ __forceinline__ float dpp_xor1(float v) {   // lane ^ 1, quad_perm [1,0,3,2]
    return __int_as_float(__builtin_amdgcn_update_dpp(
        0, __float_as_int(v), 0xB1, 0xF, 0xF, true));
}
__device__ __forceinline__ float dpp_xor2(float v) {   // lane ^ 2, quad_perm [2,3,0,1]
    return __int_as_float(__builtin_amdgcn_update_dpp(
        0, __float_as_int(v), 0x4E, 0xF, 0xF, true));
}
__device__ __forceinline__ float swz_xor4(float v) {   // ds_swizzle BitMode xor 4
    return __int_as_float(__builtin_amdgcn_ds_swizzle(__float_as_int(v), 0x101F));
}

__global__ __launch_bounds__(256, 4) void noisy_topk_router_f32(
    const float* __restrict__ x,        // [ntok,384]
    const float* __restrict__ noise,    // [ntok,8]
    const float* __restrict__ w_route,  // [8,384]
    const float* __restrict__ b_route,  // [8]
    const float* __restrict__ w_noise,  // [8,384]
    const float* __restrict__ b_noise,  // [8]
    float* __restrict__ out,            // [ntok*8 | ntok*2]
    int ntok)
{
    __shared__ float w_lds[16 * D];   // rows: e=0..7 route, e=8..15 noise
    __shared__ float bias[16];

    const int tid = threadIdx.x;

    // stage weights: 2 x 3072 floats = 2 x 768 float4; 256 threads x 3 each
#pragma unroll
    for (int r = 0; r < 3; ++r) {
        int i = (tid + 256 * r) * 4;                       // < 3072
        *(float4*)(w_lds + i)        = *(const float4*)(w_route + i);
        *(float4*)(w_lds + 3072 + i) = *(const float4*)(w_noise + i);
    }
    if (tid < 8)       bias[tid] = b_route[tid];
    else if (tid < 16) bias[tid] = b_noise[tid - 8];
    __syncthreads();

    const int wave = tid >> 6;
    const int lane = tid & 63;
    const int tg   = lane >> 3;       // token-group 0..7 (8 lanes each)
    const int c    = lane & 7;        // d-slice 0..7
    // group handles 1 token; wave covers 8; block covers 32
    const int token = blockIdx.x * 32 + wave * 8 + tg;

    v2f acc2[16];
#pragma unroll
    for (int e = 0; e < 16; ++e) acc2[e] = (v2f)(0.f);

    // chunk q (0..11): lane c covers d = q*32 + c*4 .. +4
    const float* xr = x + (size_t)token * D + c * 4;

    float4 xa[3], xb[3];
#pragma unroll
    for (int qq = 0; qq < 3; ++qq)
        xa[qq] = *(const float4*)(xr + qq * 32);

#pragma unroll
    for (int s = 0; s < 4; ++s) {
        // prefetch next superstep (s=3: dummy re-read of chunk 0..2, L1-hot)
        const int qn = (s < 3) ? (s + 1) * 3 : 0;
#pragma unroll
        for (int qq = 0; qq < 3; ++qq)
            xb[qq] = *(const float4*)(xr + (qn + qq) * 32);
        // consume current superstep from registers
#pragma unroll
        for (int qq = 0; qq < 3; ++qq) {
            const int q = s * 3 + qq;
            const float* wj = w_lds + q * 32 + c * 4;
            v2f xlo = {xa[qq].x, xa[qq].y};
            v2f xhi = {xa[qq].z, xa[qq].w};
#pragma unroll
            for (int e = 0; e < 16; ++e) {
                float4 wv = *(const float4*)(wj + e * D);   // 8-way broadcast
                v2f wlo = {wv.x, wv.y};
                v2f whi = {wv.z, wv.w};
                pk_fma(acc2[e], xlo, wlo);
                pk_fma(acc2[e], xhi, whi);
            }
        }
#pragma unroll
        for (int qq = 0; qq < 3; ++qq) xa[qq] = xb[qq];
    }

    // collapse packed halves, then partitioned reduction over 8 d-slices:
    // xor1 + xor2 (DPP, VALU pipe) + xor4 (ds_swizzle).
    float a1[16];
#pragma unroll
    for (int e = 0; e < 16; ++e) a1[e] = acc2[e].x + acc2[e].y;
#pragma unroll
    for (int e = 0; e < 16; ++e) a1[e] += dpp_xor1(a1[e]);
#pragma unroll
    for (int e = 0; e < 16; ++e) a1[e] += dpp_xor2(a1[e]);
#pragma unroll
    for (int e = 0; e < 16; ++e) a1[e] += swz_xor4(a1[e]);
    // every lane of the group holds full sums for its token

    if (c == 0) {
        float4 n0 = *(const float4*)(noise + (size_t)token * 8);
        float4 n1 = *(const float4*)(noise + (size_t)token * 8 + 4);
        float nz[8] = {n0.x, n0.y, n0.z, n0.w, n1.x, n1.y, n1.z, n1.w};

        float noisy[8];
#pragma unroll
        for (int e = 0; e < 8; ++e) {
            float lg = a1[e] + bias[e];
            float nl = a1[8 + e] + bias[8 + e];
            // stable softplus: max(z,0) + log1p(exp(-|z|))
            float sp = fmaxf(nl, 0.f) + log1pf(expf(-fabsf(nl)));
            noisy[e] = lg + nz[e] * sp;
        }

        // top-2, jax.lax.top_k tie-break: earliest index wins ties
        float v0 = noisy[0]; int i0 = 0;
#pragma unroll
        for (int e = 1; e < 8; ++e)
            if (noisy[e] > v0) { v0 = noisy[e]; i0 = e; }
        float v1 = -INFINITY; int i1 = 0;
#pragma unroll
        for (int e = 0; e < 8; ++e)
            if (e != i0 && noisy[e] > v1) { v1 = noisy[e]; i1 = e; }

        // 2-way softmax (other experts exactly 0)
        float ex  = expf(v1 - v0);       // v1 <= v0
        float inv = 1.f / (1.f + ex);
        float p0  = inv;
        float p1  = ex * inv;

        float pr[8];
#pragma unroll
        for (int e = 0; e < 8; ++e)
            pr[e] = (e == i0) ? p0 : ((e == i1) ? p1 : 0.f);

        float* orow = out + (size_t)token * 8;
        *(float4*)(orow)     = make_float4(pr[0], pr[1], pr[2], pr[3]);
        *(float4*)(orow + 4) = make_float4(pr[4], pr[5], pr[6], pr[7]);

        *(float2*)(out + (size_t)ntok * 8 + (size_t)token * 2) =
            make_float2((float)i0, (float)i1);
    }
}

extern "C" void kernel_launch(void* const* d_in, const int* in_sizes, int n_in,
                              void* d_out, int out_size, void* d_ws, size_t ws_size,
                              hipStream_t stream) {
    const float* x       = (const float*)d_in[0];
    const float* noise   = (const float*)d_in[1];
    const float* w_route = (const float*)d_in[2];
    const float* b_route = (const float*)d_in[3];
    const float* w_noise = (const float*)d_in[4];
    const float* b_noise = (const float*)d_in[5];
    float* out = (float*)d_out;

    const int ntok   = in_sizes[0] / D;   // 65536
    const int blocks = ntok / 32;         // 32 tokens per 256-thread block

    hipLaunchKernelGGL(noisy_topk_router_f32, dim3(blocks), dim3(256), 0, stream,
                       x, noise, w_route, b_route, w_noise, b_noise, out, ntok);
}

// Round 7
// 172.963 us; speedup vs baseline: 1.3853x; 1.0025x over previous
//
#include <hip/hip_runtime.h>
#include <math.h>

// NoisyTopkRouter, all-f32.
// x[ntok,384] @ {w_route,w_noise}[8,384]^T -> 16 logits/token,
// noisy = logit + noise*softplus(noise_logit), top-2 of 8, sparse softmax.
// Output: [ntok*8 probs f32 | ntok*2 indices-as-f32].
//
// R13: R12 (pk_fma) was duration-null but dropped VALU time 27->20us ->
// LDS is the dominant pipe: 192 ds_read_b128/wave for 8 tokens = 31us/CU.
// reads/token = 192/(group_width x T). All variants used group=8. This
// round: GROUP=16 lanes, T=2 tokens -> still 8 tok/wave (keeps R9's
// 2048-block TLP) but chunk spans 64 dims -> 96 b128 reads/wave (HALVED),
// each 256B-distinct, 2-way bank alias (free, m136). pk_fma unchanged
// (384/wave). W2{lo,hi} struct loads let packed halves alias the b128
// destination pairs (kill R12's float4->v2f movs). Reduction: xor1
// (partitioned, DPP) + xor2 (DPP) + xor4/xor8 (ds_swizzle).
// Prediction: VGPR ~100-115 no spill, LDS time 31->~14us, kernel 60.8 ->
// 42-48us, dur ~152-162. Kernel-null despite halved LDS => composite
// roofline, declare.

constexpr int D = 384;

typedef float v2f __attribute__((ext_vector_type(2)));

struct alignas(16) W2 { v2f lo, hi; };   // maps a b128 load as two v2f pairs

__device__ __forceinline__ void pk_fma(v2f& a, v2f b, v2f c) {
    // a = b * c + a  (2x f32 per issue, VOP3P)
    asm("v_pk_fma_f32 %0, %1, %2, %0" : "+v"(a) : "v"(b), "v"(c));
}

__device__ __forceinline__ float dpp_xor1(float v) {   // lane ^ 1, quad_perm [1,0,3,2]
    return __int_as_float(__builtin_amdgcn_update_dpp(
        0, __float_as_int(v), 0xB1, 0xF, 0xF, true));
}
__device__ __forceinline__ float dpp_xor2(float v) {   // lane ^ 2, quad_perm [2,3,0,1]
    return __int_as_float(__builtin_amdgcn_update_dpp(
        0, __float_as_int(v), 0x4E, 0xF, 0xF, true));
}
__device__ __forceinline__ float swz_xor4(float v) {   // ds_swizzle BitMode xor 4
    return __int_as_float(__builtin_amdgcn_ds_swizzle(__float_as_int(v), 0x101F));
}
__device__ __forceinline__ float swz_xor8(float v) {   // ds_swizzle BitMode xor 8
    return __int_as_float(__builtin_amdgcn_ds_swizzle(__float_as_int(v), 0x201F));
}

__global__ __launch_bounds__(256, 4) void noisy_topk_router_f32(
    const float* __restrict__ x,        // [ntok,384]
    const float* __restrict__ noise,    // [ntok,8]
    const float* __restrict__ w_route,  // [8,384]
    const float* __restrict__ b_route,  // [8]
    const float* __restrict__ w_noise,  // [8,384]
    const float* __restrict__ b_noise,  // [8]
    float* __restrict__ out,            // [ntok*8 | ntok*2]
    int ntok)
{
    __shared__ float w_lds[16 * D];   // rows: e=0..7 route, e=8..15 noise
    __shared__ float bias[16];

    const int tid = threadIdx.x;

    // stage weights: 2 x 3072 floats = 2 x 768 float4; 256 threads x 3 each
#pragma unroll
    for (int r = 0; r < 3; ++r) {
        int i = (tid + 256 * r) * 4;                       // < 3072
        *(float4*)(w_lds + i)        = *(const float4*)(w_route + i);
        *(float4*)(w_lds + 3072 + i) = *(const float4*)(w_noise + i);
    }
    if (tid < 8)       bias[tid] = b_route[tid];
    else if (tid < 16) bias[tid] = b_noise[tid - 8];
    __syncthreads();

    const int wave = tid >> 6;
    const int lane = tid & 63;
    const int g    = lane >> 4;       // token-group 0..3 (16 lanes each)
    const int c    = lane & 15;       // d-slice 0..15
    // group handles 2 tokens; wave covers 8; block covers 32
    const int tok0 = blockIdx.x * 32 + wave * 8 + g * 2;

    v2f acc[2][16];
#pragma unroll
    for (int t = 0; t < 2; ++t)
#pragma unroll
        for (int e = 0; e < 16; ++e) acc[t][e] = (v2f)(0.f);

    // chunk q (0..5): lane c covers d = q*64 + c*4 .. +4
    const float* xr = x + (size_t)tok0 * D + c * 4;

#pragma unroll
    for (int q = 0; q < 6; ++q) {
        W2 xt0 = *(const W2*)(xr + q * 64);
        W2 xt1 = *(const W2*)(xr + q * 64 + D);
        const float* wb = w_lds + q * 64 + c * 4;
#pragma unroll
        for (int e = 0; e < 16; ++e) {
            W2 w = *(const W2*)(wb + e * D);   // 256B distinct, 4-way bcast
            pk_fma(acc[0][e], xt0.lo, w.lo);
            pk_fma(acc[0][e], xt0.hi, w.hi);
            pk_fma(acc[1][e], xt1.lo, w.lo);
            pk_fma(acc[1][e], xt1.hi, w.hi);
        }
    }

    // collapse packed halves
    float f0[16], f1[16];
#pragma unroll
    for (int e = 0; e < 16; ++e) {
        f0[e] = acc[0][e].x + acc[0][e].y;
        f1[e] = acc[1][e].x + acc[1][e].y;
    }

    // partitioned reduction over the 16 d-slices:
    // xor1: keep the token matching bit0 of c (DPP) -> 16 values
    // xor2 (DPP) + xor4 + xor8 (ds_swizzle): plain reduce.
    const bool b0 = (c & 1);
    float a1[16];
#pragma unroll
    for (int e = 0; e < 16; ++e) {
        float s = b0 ? f0[e] : f1[e];   // send the token we don't keep
        float k = b0 ? f1[e] : f0[e];   // keep token tok0 + (c&1)
        a1[e] = k + dpp_xor1(s);
    }
#pragma unroll
    for (int e = 0; e < 16; ++e) a1[e] += dpp_xor2(a1[e]);
#pragma unroll
    for (int e = 0; e < 16; ++e) a1[e] += swz_xor4(a1[e]);
#pragma unroll
    for (int e = 0; e < 16; ++e) a1[e] += swz_xor8(a1[e]);
    // lanes c<2 hold full sums for token tok0 + c

    if (c < 2) {
        const int token = tok0 + c;
        float4 n0 = *(const float4*)(noise + (size_t)token * 8);
        float4 n1 = *(const float4*)(noise + (size_t)token * 8 + 4);
        float nz[8] = {n0.x, n0.y, n0.z, n0.w, n1.x, n1.y, n1.z, n1.w};

        float noisy[8];
#pragma unroll
        for (int e = 0; e < 8; ++e) {
            float lg = a1[e] + bias[e];
            float nl = a1[8 + e] + bias[8 + e];
            // stable softplus: max(z,0) + log1p(exp(-|z|))
            float sp = fmaxf(nl, 0.f) + log1pf(expf(-fabsf(nl)));
            noisy[e] = lg + nz[e] * sp;
        }

        // top-2, jax.lax.top_k tie-break: earliest index wins ties
        float v0 = noisy[0]; int i0 = 0;
#pragma unroll
        for (int e = 1; e < 8; ++e)
            if (noisy[e] > v0) { v0 = noisy[e]; i0 = e; }
        float v1 = -INFINITY; int i1 = 0;
#pragma unroll
        for (int e = 0; e < 8; ++e)
            if (e != i0 && noisy[e] > v1) { v1 = noisy[e]; i1 = e; }

        // 2-way softmax (other experts exactly 0)
        float ex  = expf(v1 - v0);       // v1 <= v0
        float inv = 1.f / (1.f + ex);
        float p0  = inv;
        float p1  = ex * inv;

        float pr[8];
#pragma unroll
        for (int e = 0; e < 8; ++e)
            pr[e] = (e == i0) ? p0 : ((e == i1) ? p1 : 0.f);

        float* orow = out + (size_t)token * 8;
        *(float4*)(orow)     = make_float4(pr[0], pr[1], pr[2], pr[3]);
        *(float4*)(orow + 4) = make_float4(pr[4], pr[5], pr[6], pr[7]);

        *(float2*)(out + (size_t)ntok * 8 + (size_t)token * 2) =
            make_float2((float)i0, (float)i1);
    }
}

extern "C" void kernel_launch(void* const* d_in, const int* in_sizes, int n_in,
                              void* d_out, int out_size, void* d_ws, size_t ws_size,
                              hipStream_t stream) {
    const float* x       = (const float*)d_in[0];
    const float* noise   = (const float*)d_in[1];
    const float* w_route = (const float*)d_in[2];
    const float* b_route = (const float*)d_in[3];
    const float* w_noise = (const float*)d_in[4];
    const float* b_noise = (const float*)d_in[5];
    float* out = (float*)d_out;

    const int ntok   = in_sizes[0] / D;   // 65536
    const int blocks = ntok / 32;         // 32 tokens per 256-thread block

    hipLaunchKernelGGL(noisy_topk_router_f32, dim3(blocks), dim3(256), 0, stream,
                       x, noise, w_route, b_route, w_noise, b_noise, out, ntok);
}